// Round 13
// baseline (1147.868 us; speedup 1.0000x reference)
//
#include <hip/hip_runtime.h>
#include <hip/hip_bf16.h>
#include <math.h>

#define B_    256
#define T_    60
#define TTOT  80
#define DIN   2048
#define D_    512
#define H_    512
#define G4    2048    // 4*H
#define M1    15360   // B_*T_

typedef __bf16 bf16x8 __attribute__((ext_vector_type(8)));
typedef __bf16 bf16x4 __attribute__((ext_vector_type(4)));
typedef float  f32x4  __attribute__((ext_vector_type(4)));

// ---------------- fused prep: 3x weight cvt + bias sum ----------------
__global__ __launch_bounds__(256) void k_prep(const float* __restrict__ We,
                                              const float* __restrict__ Wi,
                                              const float* __restrict__ Wh,
                                              __bf16* __restrict__ Web,
                                              __bf16* __restrict__ Wib,
                                              __bf16* __restrict__ Whb,
                                              const float* __restrict__ bi,
                                              const float* __restrict__ bh,
                                              float* __restrict__ bsum) {
  const int blk = blockIdx.x, tid = threadIdx.x;
  if (blk < 3072) {
    const float* s; __bf16* d; int base;
    if (blk < 1024)      { s = We; d = Web; base = blk; }
    else if (blk < 2048) { s = Wi; d = Wib; base = blk - 1024; }
    else                 { s = Wh; d = Whb; base = blk - 2048; }
    int i = (base * 256 + tid) * 4;
    float4 f = *(const float4*)(s + i);
    bf16x4 v;
    v[0] = (__bf16)f.x; v[1] = (__bf16)f.y; v[2] = (__bf16)f.z; v[3] = (__bf16)f.w;
    *(bf16x4*)(d + i) = v;
  } else {
    int i = (blk - 3072) * 256 + tid;
    if (i < G4) bsum[i] = bi[i] + bh[i];
  }
}

// ---------------- MFMA GEMM: C[m,n] = sum_k bf16(A'[m,k]) * B[n,k]  (+bias)
// A f32 [M][lda]; A' = alpha ? alpha[m/T_][k]*A : A.  B bf16 [N][K].
// 128x128 tile, BK=64, 4 waves, wave = 4x4 tiles of 16x16x32.
// XCD swizzle (T1). XT: row m=(b*T+t), col n=(g*512+jj) -> xW4[((t*B+b)*512+jj)*4+g].
template<bool ALPHA, bool OUTBF, bool XT>
__global__ __launch_bounds__(256) void k_mm(const float* __restrict__ A, int lda,
                                            const __bf16* __restrict__ Bm,
                                            const float* __restrict__ bias0,
                                            const float* __restrict__ bias1,
                                            const float* __restrict__ alpha,
                                            void* __restrict__ Cout,
                                            int N, int K) {
  __shared__ __bf16 As[128 * 64];
  __shared__ __bf16 Bs[128 * 64];
  const int tid  = threadIdx.x;
  const int lane = tid & 63;
  const int wv   = tid >> 6;
  const int wm   = wv >> 1, wn = wv & 1;
  const int la   = lane & 15, lk = lane >> 4;

  int lin = blockIdx.y * gridDim.x + blockIdx.x;
  const int nwg = gridDim.x * gridDim.y;
  if ((nwg & 7) == 0) {
    int q = nwg >> 3;
    lin = (lin & 7) * q + (lin >> 3);
  }
  const int n0 = (lin % gridDim.x) * 128;
  const int m0 = (lin / gridDim.x) * 128;

  f32x4 acc[4][4];
  #pragma unroll
  for (int i = 0; i < 4; i++)
    #pragma unroll
    for (int j = 0; j < 4; j++) acc[i][j] = (f32x4){0.f, 0.f, 0.f, 0.f};

  for (int kt = 0; kt < K; kt += 64) {
    __syncthreads();
    #pragma unroll
    for (int i = 0; i < 4; i++) {          // stage A (f32 -> bf16)
      int idx = tid + i * 256;
      int row = idx >> 3, gk = idx & 7;
      const float* src = A + (size_t)(m0 + row) * lda + kt + gk * 8;
      float4 f0 = *(const float4*)src;
      float4 f1 = *(const float4*)(src + 4);
      if (ALPHA) {
        int b = (m0 + row) / T_;
        const float* ap = alpha + (size_t)b * K + kt + gk * 8;
        float4 a0 = *(const float4*)ap;
        float4 a1 = *(const float4*)(ap + 4);
        f0.x *= a0.x; f0.y *= a0.y; f0.z *= a0.z; f0.w *= a0.w;
        f1.x *= a1.x; f1.y *= a1.y; f1.z *= a1.z; f1.w *= a1.w;
      }
      bf16x8 v;
      v[0] = (__bf16)f0.x; v[1] = (__bf16)f0.y; v[2] = (__bf16)f0.z; v[3] = (__bf16)f0.w;
      v[4] = (__bf16)f1.x; v[5] = (__bf16)f1.y; v[6] = (__bf16)f1.z; v[7] = (__bf16)f1.w;
      *(bf16x8*)(As + row * 64 + ((gk ^ (row & 7)) << 3)) = v;
    }
    #pragma unroll
    for (int i = 0; i < 4; i++) {          // stage B (bf16 direct)
      int idx = tid + i * 256;
      int row = idx >> 3, gk = idx & 7;
      bf16x8 v = *(const bf16x8*)(Bm + (size_t)(n0 + row) * K + kt + gk * 8);
      *(bf16x8*)(Bs + row * 64 + ((gk ^ (row & 7)) << 3)) = v;
    }
    __syncthreads();
    #pragma unroll
    for (int ks = 0; ks < 2; ks++) {
      bf16x8 af[4], bfr[4];
      #pragma unroll
      for (int i = 0; i < 4; i++) {
        int row = wm * 64 + i * 16 + la;
        af[i] = *(const bf16x8*)(As + row * 64 + (((ks * 4 + lk) ^ (row & 7)) << 3));
      }
      #pragma unroll
      for (int j = 0; j < 4; j++) {
        int row = wn * 64 + j * 16 + la;
        bfr[j] = *(const bf16x8*)(Bs + row * 64 + (((ks * 4 + lk) ^ (row & 7)) << 3));
      }
      #pragma unroll
      for (int i = 0; i < 4; i++)
        #pragma unroll
        for (int j = 0; j < 4; j++)
          acc[i][j] = __builtin_amdgcn_mfma_f32_16x16x32_bf16(af[i], bfr[j], acc[i][j], 0, 0, 0);
    }
  }
  #pragma unroll
  for (int j = 0; j < 4; j++) {
    int col = n0 + wn * 64 + j * 16 + la;
    float bb = bias0[col] + (bias1 ? bias1[col] : 0.f);
    #pragma unroll
    for (int i = 0; i < 4; i++) {
      int rbase = m0 + wm * 64 + i * 16 + lk * 4;
      #pragma unroll
      for (int r = 0; r < 4; r++) {
        float v = acc[i][j][r] + bb;
        int m = rbase + r;
        if (XT) {
          int b = m / T_, tt = m % T_;
          int g = col >> 9, jj = col & 511;
          ((__bf16*)Cout)[(((size_t)tt * B_ + b) * 512 + jj) * 4 + g] = (__bf16)v;
        } else if (OUTBF) {
          ((__bf16*)Cout)[(size_t)m * N + col] = (__bf16)v;
        } else {
          ((float*)Cout)[(size_t)m * N + col] = v;
        }
      }
    }
  }
}

// ---------------- per-feature mean/var partials ----------------
__global__ __launch_bounds__(256) void k_stats_partial(const float* __restrict__ V,
                                                       float* __restrict__ part) {
  const int blk = blockIdx.x;
  const int tid = threadIdx.x;
  float s0 = 0.f, s1 = 0.f, q0 = 0.f, q1 = 0.f;
  const float* p = V + (size_t)blk * 64 * D_;
  for (int r = 0; r < 64; r++) {
    float a = p[(size_t)r * D_ + tid];
    float b = p[(size_t)r * D_ + tid + 256];
    s0 += a; q0 += a * a;
    s1 += b; q1 += b * b;
  }
  part[(size_t)blk * 1024 + tid]             = s0;
  part[(size_t)blk * 1024 + tid + 256]       = s1;
  part[(size_t)blk * 1024 + 512 + tid]       = q0;
  part[(size_t)blk * 1024 + 512 + tid + 256] = q1;
}

__global__ __launch_bounds__(512) void k_stats_final(const float* __restrict__ part,
                                                     float* __restrict__ stats) {
  const int d = threadIdx.x;
  float s = 0.f, q = 0.f;
  for (int r = 0; r < 240; r++) {
    s += part[(size_t)r * 1024 + d];
    q += part[(size_t)r * 1024 + 512 + d];
  }
  float mean = s * (1.f / 15360.f);
  float var  = q * (1.f / 15360.f) - mean * mean;
  stats[d]        = mean;
  stats[512 + d]  = 1.f / sqrtf(var + 1e-5f);
}

// ---------------- fused normalize (in place) + vscore + softmax -> alpha -------
// w_h, w_s, b_attn cancel in softmax(axis=1) (per-row shift) -> omitted.
__global__ __launch_bounds__(512) void k_norm_alpha(float* __restrict__ V,
                                                    const float* __restrict__ stats,
                                                    const float* __restrict__ gamma,
                                                    const float* __restrict__ beta,
                                                    const float* __restrict__ w_attn,
                                                    float* __restrict__ alpha) {
  const int b = blockIdx.x, d = threadIdx.x;
  __shared__ float wv[T_];
  __shared__ float red[8];
  if (d < T_) wv[d] = w_attn[2 * H_ + d];
  __syncthreads();
  const float mean = stats[d], rstd = stats[512 + d];
  const float ga = gamma[d], be = beta[d];
  float vs = 0.f;
  float* p = V + (size_t)b * T_ * D_ + d;
  for (int t = 0; t < T_; t++) {
    float x = p[(size_t)t * D_];
    float xn = (x - mean) * rstd * ga + be;
    p[(size_t)t * D_] = xn;
    vs += wv[t] * xn;
  }
  float m = vs;
  #pragma unroll
  for (int o = 32; o >= 1; o >>= 1) m = fmaxf(m, __shfl_xor(m, o));
  if ((d & 63) == 0) red[d >> 6] = m;
  __syncthreads();
  float M = red[0];
  #pragma unroll
  for (int w = 1; w < 8; w++) M = fmaxf(M, red[w]);
  float e = expf(vs - M);
  float s = e;
  #pragma unroll
  for (int o = 32; o >= 1; o >>= 1) s += __shfl_xor(s, o);
  __syncthreads();
  if ((d & 63) == 0) red[d >> 6] = s;
  __syncthreads();
  float S = 0.f;
  #pragma unroll
  for (int w = 0; w < 8; w++) S += red[w];
  alpha[(size_t)b * D_ + d] = e / S;
}

// ---------------- persistent recurrence v10: epoch-TAGGED h (data == flag) -----
// R8 structure (256 WGs x 256 thr, group = blockIdx%8 owns 32 b-rows as 2
// pipelined subtiles, wave = gate, W_hh LDS-resident) but h is exchanged as
// tagged u32 words: (epoch<<16)|bf16bits, parity-2 buffer. Consumers retry-load
// until tag==t -> ONE L3 RT per phase instead of flag-RT + load-RT. No flag
// stores, no vmcnt drains. Parity proof (transitive, as R8): seeing all tags==t
// on parity t&1 implies every group WG finished step t-1, hence finished
// reading parity (t-1)&1 == (t+1)&1, so writing h(t+1) there is safe.
// Poisoned tags (0xAAAA) never match 1..79 -> no buffer init needed.
__device__ __forceinline__ float sigf(float x) { return 1.f / (1.f + expf(-x)); }

__global__ __launch_bounds__(256, 1) void k_rec(const __bf16* __restrict__ Whh,
                                                const __bf16* __restrict__ xW4, // [t][b][j][4]
                                                const float* __restrict__ bsum,
                                                unsigned* __restrict__ htag,    // 2 * B_*H_ u32
                                                float* __restrict__ out) {
  const int tid  = threadIdx.x;
  const int lane = tid & 63;
  const int widx = tid >> 6;          // wave = gate g
  const int grp  = blockIdx.x & 7;
  const int wg   = blockIdx.x >> 3;   // 0..31 j-slice
  const int B0   = grp * 32;
  const int j0   = wg * 16;
  const int la   = lane & 15, lk = lane >> 4;

  __shared__ __bf16   wslab[4 * 16 * 520];   // W_hh slice [g][j-row][k]
  __shared__ unsigned hsin[16 * 260];        // untagged h subtile, u32 = 2 bf16, pad 260
  __shared__ float    gatesL[4 * 256];       // pre-activations [g][b*16+j]

  // one-time W_hh preload: wave g loads rows g*512+j0..+15
  #pragma unroll
  for (int it = 0; it < 16; it++) {
    bf16x8 v = *(const bf16x8*)(Whh + ((size_t)(widx * 512 + j0 + it)) * 512 + lane * 8);
    *(bf16x8*)(wslab + (widx * 16 + it) * 520 + lane * 8) = v;
  }

  // cell ownership: subtile s -> b = B0 + s*16 + (tid>>4), j = j0 + (tid&15)
  const int cb = tid >> 4;
  const int cj = tid & 15;
  float bsl[4];
  #pragma unroll
  for (int g = 0; g < 4; g++) bsl[g] = bsum[g * 512 + j0 + cj];

  float creg[2] = {0.f, 0.f};

  bf16x4 xv[2];
  #pragma unroll
  for (int s = 0; s < 2; s++)
    xv[s] = *(const bf16x4*)(xW4 + (((size_t)(B0 + s * 16 + cb)) * 512 + j0 + cj) * 4);

  __syncthreads();   // wslab ready

  for (int t = 0; t < TTOT; t++) {
    const unsigned* hin  = htag + (size_t)(t & 1) * (B_ * H_);        // tag t lives here
    unsigned*       hout = htag + (size_t)((t + 1) & 1) * (B_ * H_);  // tag t+1 goes here
    const unsigned long long expect = (unsigned long long)t;

    #pragma unroll
    for (int s = 0; s < 2; s++) {
      const int s16 = s * 16;

      if (t > 0) {
        // (a) tagged cooperative load: 16x512 tagged u32 = 4096 u64; 16/thread.
        // word w: row = w>>8, pair = w&255 (j = pair*2). Retry until both tags==t.
        #pragma unroll
        for (int it = 0; it < 16; it++) {
          int w = tid + it * 256;
          int row = w >> 8, pr = w & 255;
          const unsigned long long* p =
              (const unsigned long long*)(hin + (size_t)(B0 + s16 + row) * H_) + pr;
          unsigned long long v = 0;
          for (int rt = 0; rt < (1 << 20); rt++) {
            v = __hip_atomic_load(p, __ATOMIC_RELAXED, __HIP_MEMORY_SCOPE_AGENT);
            if (((v >> 16) & 0xFFFFull) == expect && (v >> 48) == expect) break;
            __builtin_amdgcn_s_sleep(1);
          }
          hsin[row * 260 + pr] = (unsigned)(v & 0xFFFFu) | ((unsigned)((v >> 32) & 0xFFFFu) << 16);
        }
        __syncthreads();

        // (b) gate MFMA: wave g computes 16b x 16j, K=512
        f32x4 acc = (f32x4){0.f, 0.f, 0.f, 0.f};
        #pragma unroll
        for (int ks = 0; ks < 16; ks++) {
          bf16x8 w = *(const bf16x8*)(wslab + (widx * 16 + la) * 520 + ks * 32 + lk * 8);
          bf16x8 a = *(const bf16x8*)(hsin + la * 260 + ks * 16 + lk * 4);
          acc = __builtin_amdgcn_mfma_f32_16x16x32_bf16(a, w, acc, 0, 0, 0);
        }
        #pragma unroll
        for (int r = 0; r < 4; r++)
          gatesL[widx * 256 + (lk * 4 + r) * 16 + la] = acc[r];
        __syncthreads();
      }

      // (c) LSTM cell: 1 output/thread; publish tagged h (data == flag)
      float p[4];
      #pragma unroll
      for (int g = 0; g < 4; g++)
        p[g] = (t > 0 ? gatesL[g * 256 + tid] : 0.f) + (float)xv[s][g];
      float gi = sigf(p[0]), gf = sigf(p[1]), gg = tanhf(p[2]), go = sigf(p[3]);
      float cn = gf * creg[s] + gi * gg;
      creg[s] = cn;
      float hn = go * tanhf(cn);

      __bf16 hb = (__bf16)hn;
      unsigned tagged = (unsigned)*(unsigned short*)&hb | ((unsigned)(t + 1) << 16);
      __hip_atomic_store(hout + (size_t)(B0 + s16 + cb) * H_ + j0 + cj, tagged,
                         __ATOMIC_RELAXED, __HIP_MEMORY_SCOPE_AGENT);

      // (d) out store + next-step prefetch (overlaps other subtile's load)
      out[((size_t)(B0 + s16 + cb) * TTOT + t) * D_ + j0 + cj] = hn;
      if (t + 1 < T_) {
        xv[s] = *(const bf16x4*)(xW4 + (((size_t)(t + 1) * B_ + B0 + s16 + cb) * 512 + j0 + cj) * 4);
      } else {
        #pragma unroll
        for (int g = 0; g < 4; g++) xv[s][g] = (__bf16)bsl[g];
      }
    }
  }
}

extern "C" void kernel_launch(void* const* d_in, const int* in_sizes, int n_in,
                              void* d_out, int out_size, void* d_ws, size_t ws_size,
                              hipStream_t stream) {
  const float* video  = (const float*)d_in[0];
  const float* W_enc  = (const float*)d_in[2];
  const float* b_enc  = (const float*)d_in[3];
  const float* gamma  = (const float*)d_in[4];
  const float* beta   = (const float*)d_in[5];
  const float* w_attn = (const float*)d_in[6];
  const float* W_ih   = (const float*)d_in[8];
  const float* W_hh   = (const float*)d_in[9];
  const float* b_ih   = (const float*)d_in[10];
  const float* b_hh   = (const float*)d_in[11];
  float* out = (float*)d_out;

  // workspace layout (float-sized slots; ~106 MB total)
  float*    base  = (float*)d_ws;
  float*    V     = base;                    size_t off = (size_t)M1 * D_;
  float*    part  = base + off;              off += 240 * 1024;
  float*    stats = base + off;              off += 1024;
  float*    alpha = base + off;              off += (size_t)B_ * D_;
  float*    bsum  = base + off;              off += G4;
  unsigned* htag  = (unsigned*)(base + off); off += (size_t)2 * B_ * H_;  // tagged h, 1MB
  __bf16*   xWbf  = (__bf16*)(base + off);   off += (size_t)M1 * G4 / 2;
  __bf16*   Wencb = (__bf16*)(base + off);   off += (size_t)D_ * DIN / 2;
  __bf16*   Wihb  = (__bf16*)(base + off);   off += (size_t)G4 * H_ / 2;
  __bf16*   Whhb  = (__bf16*)(base + off);   off += (size_t)G4 * H_ / 2;

  // fused prep: 3x weight cvt (3072 blks) + bsum (8). No flag/buffer zeroing:
  // poisoned tags (0xAAAA) never match expected epochs 1..79.
  k_prep<<<3080, 256, 0, stream>>>(W_enc, W_ih, W_hh, Wencb, Wihb, Whhb,
                                   b_ih, b_hh, bsum);

  // encoder GEMM: V = video @ W_enc^T + b_enc  (M=15360,N=512,K=2048)
  k_mm<false, false, false><<<dim3(4, 120), 256, 0, stream>>>(
      video, DIN, Wencb, b_enc, nullptr, nullptr, V, D_, DIN);

  k_stats_partial<<<240, 256, 0, stream>>>(V, part);
  k_stats_final<<<1, 512, 0, stream>>>(part, stats);
  k_norm_alpha<<<B_, 512, 0, stream>>>(V, stats, gamma, beta, w_attn, alpha);

  // xW4[t][b][j][g] = ((alpha ⊙ Vnorm) @ W_ih^T + b_ih + b_hh), bf16
  k_mm<true, true, true><<<dim3(16, 120), 256, 0, stream>>>(
      V, D_, Wihb, b_ih, b_hh, alpha, (void*)xWbf, G4, D_);

  // all 80 recurrence steps in one persistent kernel (256 WGs x 256 thr)
  k_rec<<<256, 256, 0, stream>>>(Whhb, xWbf, bsum, htag, out);
}

// Round 14
// 540.122 us; speedup vs baseline: 2.1252x; 2.1252x over previous
//
#include <hip/hip_runtime.h>
#include <hip/hip_bf16.h>
#include <math.h>

#define B_    256
#define T_    60
#define TTOT  80
#define DIN   2048
#define D_    512
#define H_    512
#define G4    2048    // 4*H
#define M1    15360   // B_*T_

typedef __bf16 bf16x8 __attribute__((ext_vector_type(8)));
typedef __bf16 bf16x4 __attribute__((ext_vector_type(4)));
typedef float  f32x4  __attribute__((ext_vector_type(4)));

// ---------------- fused prep: 3x weight cvt + bias sum + flag zero ----------------
__global__ __launch_bounds__(256) void k_prep(const float* __restrict__ We,
                                              const float* __restrict__ Wi,
                                              const float* __restrict__ Wh,
                                              __bf16* __restrict__ Web,
                                              __bf16* __restrict__ Wib,
                                              __bf16* __restrict__ Whb,
                                              const float* __restrict__ bi,
                                              const float* __restrict__ bh,
                                              float* __restrict__ bsum,
                                              unsigned* __restrict__ flags) {
  const int blk = blockIdx.x, tid = threadIdx.x;
  if (blk < 3072) {
    const float* s; __bf16* d; int base;
    if (blk < 1024)      { s = We; d = Web; base = blk; }
    else if (blk < 2048) { s = Wi; d = Wib; base = blk - 1024; }
    else                 { s = Wh; d = Whb; base = blk - 2048; }
    int i = (base * 256 + tid) * 4;
    float4 f = *(const float4*)(s + i);
    bf16x4 v;
    v[0] = (__bf16)f.x; v[1] = (__bf16)f.y; v[2] = (__bf16)f.z; v[3] = (__bf16)f.w;
    *(bf16x4*)(d + i) = v;
  } else if (blk < 3080) {
    int i = (blk - 3072) * 256 + tid;
    bsum[i] = bi[i] + bh[i];
  } else {
    int i = (blk - 3080) * 256 + tid;   // 64 blocks -> 16384 u32 flags
    flags[i] = 0u;
  }
}

// ---------------- MFMA GEMM: C[m,n] = sum_k bf16(A'[m,k]) * B[n,k]  (+bias)
// A f32 [M][lda]; A' = alpha ? alpha[m/T_][k]*A : A.  B bf16 [N][K].
// 128x128 tile, BK=64, 4 waves, wave = 4x4 tiles of 16x16x32.
// XCD swizzle (T1). XT: row m=(b*T+t), col n=(g*512+jj) -> xW4[((t*B+b)*512+jj)*4+g].
template<bool ALPHA, bool OUTBF, bool XT>
__global__ __launch_bounds__(256) void k_mm(const float* __restrict__ A, int lda,
                                            const __bf16* __restrict__ Bm,
                                            const float* __restrict__ bias0,
                                            const float* __restrict__ bias1,
                                            const float* __restrict__ alpha,
                                            void* __restrict__ Cout,
                                            int N, int K) {
  __shared__ __bf16 As[128 * 64];
  __shared__ __bf16 Bs[128 * 64];
  const int tid  = threadIdx.x;
  const int lane = tid & 63;
  const int wv   = tid >> 6;
  const int wm   = wv >> 1, wn = wv & 1;
  const int la   = lane & 15, lk = lane >> 4;

  int lin = blockIdx.y * gridDim.x + blockIdx.x;
  const int nwg = gridDim.x * gridDim.y;
  if ((nwg & 7) == 0) {
    int q = nwg >> 3;
    lin = (lin & 7) * q + (lin >> 3);
  }
  const int n0 = (lin % gridDim.x) * 128;
  const int m0 = (lin / gridDim.x) * 128;

  f32x4 acc[4][4];
  #pragma unroll
  for (int i = 0; i < 4; i++)
    #pragma unroll
    for (int j = 0; j < 4; j++) acc[i][j] = (f32x4){0.f, 0.f, 0.f, 0.f};

  for (int kt = 0; kt < K; kt += 64) {
    __syncthreads();
    #pragma unroll
    for (int i = 0; i < 4; i++) {          // stage A (f32 -> bf16)
      int idx = tid + i * 256;
      int row = idx >> 3, gk = idx & 7;
      const float* src = A + (size_t)(m0 + row) * lda + kt + gk * 8;
      float4 f0 = *(const float4*)src;
      float4 f1 = *(const float4*)(src + 4);
      if (ALPHA) {
        int b = (m0 + row) / T_;
        const float* ap = alpha + (size_t)b * K + kt + gk * 8;
        float4 a0 = *(const float4*)ap;
        float4 a1 = *(const float4*)(ap + 4);
        f0.x *= a0.x; f0.y *= a0.y; f0.z *= a0.z; f0.w *= a0.w;
        f1.x *= a1.x; f1.y *= a1.y; f1.z *= a1.z; f1.w *= a1.w;
      }
      bf16x8 v;
      v[0] = (__bf16)f0.x; v[1] = (__bf16)f0.y; v[2] = (__bf16)f0.z; v[3] = (__bf16)f0.w;
      v[4] = (__bf16)f1.x; v[5] = (__bf16)f1.y; v[6] = (__bf16)f1.z; v[7] = (__bf16)f1.w;
      *(bf16x8*)(As + row * 64 + ((gk ^ (row & 7)) << 3)) = v;
    }
    #pragma unroll
    for (int i = 0; i < 4; i++) {          // stage B (bf16 direct)
      int idx = tid + i * 256;
      int row = idx >> 3, gk = idx & 7;
      bf16x8 v = *(const bf16x8*)(Bm + (size_t)(n0 + row) * K + kt + gk * 8);
      *(bf16x8*)(Bs + row * 64 + ((gk ^ (row & 7)) << 3)) = v;
    }
    __syncthreads();
    #pragma unroll
    for (int ks = 0; ks < 2; ks++) {
      bf16x8 af[4], bfr[4];
      #pragma unroll
      for (int i = 0; i < 4; i++) {
        int row = wm * 64 + i * 16 + la;
        af[i] = *(const bf16x8*)(As + row * 64 + (((ks * 4 + lk) ^ (row & 7)) << 3));
      }
      #pragma unroll
      for (int j = 0; j < 4; j++) {
        int row = wn * 64 + j * 16 + la;
        bfr[j] = *(const bf16x8*)(Bs + row * 64 + (((ks * 4 + lk) ^ (row & 7)) << 3));
      }
      #pragma unroll
      for (int i = 0; i < 4; i++)
        #pragma unroll
        for (int j = 0; j < 4; j++)
          acc[i][j] = __builtin_amdgcn_mfma_f32_16x16x32_bf16(af[i], bfr[j], acc[i][j], 0, 0, 0);
    }
  }
  #pragma unroll
  for (int j = 0; j < 4; j++) {
    int col = n0 + wn * 64 + j * 16 + la;
    float bb = bias0[col] + (bias1 ? bias1[col] : 0.f);
    #pragma unroll
    for (int i = 0; i < 4; i++) {
      int rbase = m0 + wm * 64 + i * 16 + lk * 4;
      #pragma unroll
      for (int r = 0; r < 4; r++) {
        float v = acc[i][j][r] + bb;
        int m = rbase + r;
        if (XT) {
          int b = m / T_, tt = m % T_;
          int g = col >> 9, jj = col & 511;
          ((__bf16*)Cout)[(((size_t)tt * B_ + b) * 512 + jj) * 4 + g] = (__bf16)v;
        } else if (OUTBF) {
          ((__bf16*)Cout)[(size_t)m * N + col] = (__bf16)v;
        } else {
          ((float*)Cout)[(size_t)m * N + col] = v;
        }
      }
    }
  }
}

// ---------------- per-feature mean/var partials ----------------
__global__ __launch_bounds__(256) void k_stats_partial(const float* __restrict__ V,
                                                       float* __restrict__ part) {
  const int blk = blockIdx.x;
  const int tid = threadIdx.x;
  float s0 = 0.f, s1 = 0.f, q0 = 0.f, q1 = 0.f;
  const float* p = V + (size_t)blk * 64 * D_;
  for (int r = 0; r < 64; r++) {
    float a = p[(size_t)r * D_ + tid];
    float b = p[(size_t)r * D_ + tid + 256];
    s0 += a; q0 += a * a;
    s1 += b; q1 += b * b;
  }
  part[(size_t)blk * 1024 + tid]             = s0;
  part[(size_t)blk * 1024 + tid + 256]       = s1;
  part[(size_t)blk * 1024 + 512 + tid]       = q0;
  part[(size_t)blk * 1024 + 512 + tid + 256] = q1;
}

__global__ __launch_bounds__(512) void k_stats_final(const float* __restrict__ part,
                                                     float* __restrict__ stats) {
  const int d = threadIdx.x;
  float s = 0.f, q = 0.f;
  for (int r = 0; r < 240; r++) {
    s += part[(size_t)r * 1024 + d];
    q += part[(size_t)r * 1024 + 512 + d];
  }
  float mean = s * (1.f / 15360.f);
  float var  = q * (1.f / 15360.f) - mean * mean;
  stats[d]        = mean;
  stats[512 + d]  = 1.f / sqrtf(var + 1e-5f);
}

// ---------------- fused normalize (in place) + vscore + softmax -> alpha -------
// w_h, w_s, b_attn cancel in softmax(axis=1) (per-row shift) -> omitted.
__global__ __launch_bounds__(512) void k_norm_alpha(float* __restrict__ V,
                                                    const float* __restrict__ stats,
                                                    const float* __restrict__ gamma,
                                                    const float* __restrict__ beta,
                                                    const float* __restrict__ w_attn,
                                                    float* __restrict__ alpha) {
  const int b = blockIdx.x, d = threadIdx.x;
  __shared__ float wv[T_];
  __shared__ float red[8];
  if (d < T_) wv[d] = w_attn[2 * H_ + d];
  __syncthreads();
  const float mean = stats[d], rstd = stats[512 + d];
  const float ga = gamma[d], be = beta[d];
  float vs = 0.f;
  float* p = V + (size_t)b * T_ * D_ + d;
  for (int t = 0; t < T_; t++) {
    float x = p[(size_t)t * D_];
    float xn = (x - mean) * rstd * ga + be;
    p[(size_t)t * D_] = xn;
    vs += wv[t] * xn;
  }
  float m = vs;
  #pragma unroll
  for (int o = 32; o >= 1; o >>= 1) m = fmaxf(m, __shfl_xor(m, o));
  if ((d & 63) == 0) red[d >> 6] = m;
  __syncthreads();
  float M = red[0];
  #pragma unroll
  for (int w = 1; w < 8; w++) M = fmaxf(M, red[w]);
  float e = expf(vs - M);
  float s = e;
  #pragma unroll
  for (int o = 32; o >= 1; o >>= 1) s += __shfl_xor(s, o);
  __syncthreads();
  if ((d & 63) == 0) red[d >> 6] = s;
  __syncthreads();
  float S = 0.f;
  #pragma unroll
  for (int w = 0; w < 8; w++) S += red[w];
  alpha[(size_t)b * D_ + d] = e / S;
}

// ---------------- persistent recurrence (R8/v5 verbatim + watchdogged polls) ----
// 256 WGs x 256 thr. group = blockIdx%8 owns b-rows [grp*32,+32) as TWO
// pipelined subtiles of 16 -> each subtile's flags/h were published one phase
// earlier, hiding the L3 RTs. W_hh slice (64KB) LDS-resident (loaded once).
// h published straight from registers (2B agent store). Per-(wg,sub) epoch
// flag, plain relaxed agent store + 32-lane parallel poll (watchdog-bounded).
// Parity-2 h buffer race-free: writing h(t+3) requires all flags>=t+2 =>
// all h(t+1) reads (same parity) completed.
__device__ __forceinline__ float sigf(float x) { return 1.f / (1.f + expf(-x)); }

__global__ __launch_bounds__(256) void k_rec(const __bf16* __restrict__ Whh,
                                             const __bf16* __restrict__ xW4,  // [t][b][j][4]
                                             const float* __restrict__ bsum,
                                             __bf16* __restrict__ hbuf,       // 2 * B_*H_
                                             float* __restrict__ out,
                                             unsigned* __restrict__ bar) {
  const int tid  = threadIdx.x;
  const int lane = tid & 63;
  const int widx = tid >> 6;          // wave = gate g
  const int grp  = blockIdx.x & 7;    // 8 groups (XCD-affine heuristic)
  const int wg   = blockIdx.x >> 3;   // 0..31 within group
  const int B0   = grp * 32;
  const int j0   = wg * 16;
  const int la   = lane & 15, lk = lane >> 4;

  __shared__ __bf16 wslab[4 * 16 * 520];   // W_hh slice [g][j-row][k]
  __shared__ __bf16 hsin[16 * 520];        // staged h subtile (16 rows)
  __shared__ float  gatesL[4 * 256];       // pre-activations [g][b*16+j]

  // one-time W_hh preload: wave g loads rows g*512+j0..+15 (16KB each)
  #pragma unroll
  for (int it = 0; it < 16; it++) {
    bf16x8 v = *(const bf16x8*)(Whh + ((size_t)(widx * 512 + j0 + it)) * 512 + lane * 8);
    *(bf16x8*)(wslab + (widx * 16 + it) * 520 + lane * 8) = v;
  }

  // cell ownership: subtile s -> b = B0 + s*16 + (tid>>4), j = j0 + (tid&15)
  const int cb = tid >> 4;
  const int cj = tid & 15;
  float bsl[4];
  #pragma unroll
  for (int g = 0; g < 4; g++) bsl[g] = bsum[g * 512 + j0 + cj];

  float creg[2] = {0.f, 0.f};
  unsigned* slots = bar + (size_t)grp * 64 * 32;   // (wg*2+s)*32 stride 128B

  // prefetch additive terms for t=0 (both subtiles)
  bf16x4 xv[2];
  #pragma unroll
  for (int s = 0; s < 2; s++)
    xv[s] = *(const bf16x4*)(xW4 + (((size_t)(B0 + s * 16 + cb)) * 512 + j0 + cj) * 4);

  for (int t = 0; t < TTOT; t++) {
    const __bf16* hin  = hbuf + (size_t)(t & 1) * (B_ * H_);
    __bf16*       hout = hbuf + (size_t)((t + 1) & 1) * (B_ * H_);

    #pragma unroll
    for (int s = 0; s < 2; s++) {
      const int s16 = s * 16;

      if (t > 0) {
        // (a) wait: lane w polls WG w's flag for this subtile (watchdogged)
        if (tid < 32) {
          unsigned* p = slots + (tid * 2 + s) * 32;
          for (int it = 0; it < (1 << 22); it++) {
            if (__hip_atomic_load(p, __ATOMIC_RELAXED,
                                  __HIP_MEMORY_SCOPE_AGENT) >= (unsigned)t)
              break;
            __builtin_amdgcn_s_sleep(1);
          }
        }
        __syncthreads();

        // (b) stage h subtile (16x512 bf16 = 16KB): batched 8B coherent loads
        unsigned long long vbuf[8];
        #pragma unroll
        for (int it = 0; it < 8; it++) {
          int idx = tid + it * 256;            // 2048 8B-words
          int row = idx >> 7, col4 = (idx & 127) * 4;
          vbuf[it] = __hip_atomic_load(
              (const unsigned long long*)(hin + (size_t)(B0 + s16 + row) * H_ + col4),
              __ATOMIC_RELAXED, __HIP_MEMORY_SCOPE_AGENT);
        }
        #pragma unroll
        for (int it = 0; it < 8; it++) {
          int idx = tid + it * 256;
          int row = idx >> 7, col4 = (idx & 127) * 4;
          *(unsigned long long*)(hsin + row * 520 + col4) = vbuf[it];
        }
        __syncthreads();

        // (c) gate MFMA: wave g computes 16b x 16j, K=512
        f32x4 acc = (f32x4){0.f, 0.f, 0.f, 0.f};
        #pragma unroll
        for (int ks = 0; ks < 16; ks++) {
          bf16x8 w = *(const bf16x8*)(wslab + (widx * 16 + la) * 520 + ks * 32 + lk * 8);
          bf16x8 a = *(const bf16x8*)(hsin + la * 520 + ks * 32 + lk * 8);
          acc = __builtin_amdgcn_mfma_f32_16x16x32_bf16(a, w, acc, 0, 0, 0);
        }
        #pragma unroll
        for (int r = 0; r < 4; r++)
          gatesL[widx * 256 + (lk * 4 + r) * 16 + la] = acc[r];
        __syncthreads();
      }

      // LSTM cell: 1 output/thread
      float p[4];
      #pragma unroll
      for (int g = 0; g < 4; g++)
        p[g] = (t > 0 ? gatesL[g * 256 + tid] : 0.f) + (float)xv[s][g];
      float gi = sigf(p[0]), gf = sigf(p[1]), gg = tanhf(p[2]), go = sigf(p[3]);
      float cn = gf * creg[s] + gi * gg;
      creg[s] = cn;
      float hn = go * tanhf(cn);

      // publish h(t+1) straight from register (2B coherent store)
      __bf16 hb = (__bf16)hn;
      __hip_atomic_store((unsigned short*)(hout + (size_t)(B0 + s16 + cb) * H_ + j0 + cj),
                         *(unsigned short*)&hb,
                         __ATOMIC_RELAXED, __HIP_MEMORY_SCOPE_AGENT);
      asm volatile("s_waitcnt vmcnt(0)" ::: "memory");
      __syncthreads();
      if (tid == 0)
        __hip_atomic_store(slots + (wg * 2 + s) * 32, (unsigned)(t + 1),
                           __ATOMIC_RELAXED, __HIP_MEMORY_SCOPE_AGENT);

      // out store + next-step prefetch AFTER flag (overlaps other subtile)
      out[((size_t)(B0 + s16 + cb) * TTOT + t) * D_ + j0 + cj] = hn;
      if (t + 1 < T_) {
        xv[s] = *(const bf16x4*)(xW4 + (((size_t)(t + 1) * B_ + B0 + s16 + cb) * 512 + j0 + cj) * 4);
      } else {
        #pragma unroll
        for (int g = 0; g < 4; g++) xv[s][g] = (__bf16)bsl[g];
      }
    }
  }
}

extern "C" void kernel_launch(void* const* d_in, const int* in_sizes, int n_in,
                              void* d_out, int out_size, void* d_ws, size_t ws_size,
                              hipStream_t stream) {
  const float* video  = (const float*)d_in[0];
  const float* W_enc  = (const float*)d_in[2];
  const float* b_enc  = (const float*)d_in[3];
  const float* gamma  = (const float*)d_in[4];
  const float* beta   = (const float*)d_in[5];
  const float* w_attn = (const float*)d_in[6];
  const float* W_ih   = (const float*)d_in[8];
  const float* W_hh   = (const float*)d_in[9];
  const float* b_ih   = (const float*)d_in[10];
  const float* b_hh   = (const float*)d_in[11];
  float* out = (float*)d_out;

  // workspace layout (float-sized slots; ~105 MB total)
  float*    base  = (float*)d_ws;
  float*    V     = base;                    size_t off = (size_t)M1 * D_;
  float*    part  = base + off;              off += 240 * 1024;
  float*    stats = base + off;              off += 1024;
  float*    alpha = base + off;              off += (size_t)B_ * D_;
  float*    bsum  = base + off;              off += G4;
  __bf16*   hbuf  = (__bf16*)(base + off);   off += (size_t)2 * B_ * H_ / 2;
  unsigned* bar   = (unsigned*)(base + off); off += 16384;  // 8grp x 64slot x 128B
  __bf16*   xWbf  = (__bf16*)(base + off);   off += (size_t)M1 * G4 / 2;
  __bf16*   Wencb = (__bf16*)(base + off);   off += (size_t)D_ * DIN / 2;
  __bf16*   Wihb  = (__bf16*)(base + off);   off += (size_t)G4 * H_ / 2;
  __bf16*   Whhb  = (__bf16*)(base + off);   off += (size_t)G4 * H_ / 2;

  // fused prep: 3x weight cvt (3072 blks) + bsum (8) + zero flags (64)
  k_prep<<<3144, 256, 0, stream>>>(W_enc, W_ih, W_hh, Wencb, Wihb, Whhb,
                                   b_ih, b_hh, bsum, bar);

  // encoder GEMM: V = video @ W_enc^T + b_enc  (M=15360,N=512,K=2048)
  k_mm<false, false, false><<<dim3(4, 120), 256, 0, stream>>>(
      video, DIN, Wencb, b_enc, nullptr, nullptr, V, D_, DIN);

  k_stats_partial<<<240, 256, 0, stream>>>(V, part);
  k_stats_final<<<1, 512, 0, stream>>>(part, stats);
  k_norm_alpha<<<B_, 512, 0, stream>>>(V, stats, gamma, beta, w_attn, alpha);

  // xW4[t][b][j][g] = ((alpha ⊙ Vnorm) @ W_ih^T + b_ih + b_hh), bf16
  k_mm<true, true, true><<<dim3(16, 120), 256, 0, stream>>>(
      V, D_, Wihb, b_ih, b_hh, alpha, (void*)xWbf, G4, D_);

  // all 80 recurrence steps in one persistent kernel (256 WGs x 256 thr)
  k_rec<<<256, 256, 0, stream>>>(Whhb, xWbf, bsum, hbuf, out, bar);
}